// Round 4
// baseline (1066.866 us; speedup 1.0000x reference)
//
#include <hip/hip_runtime.h>
#include <hip/hip_bf16.h>

typedef __attribute__((ext_vector_type(8))) _Float16 f16x8;
typedef __attribute__((ext_vector_type(4))) float f32x4;
typedef __attribute__((ext_vector_type(4))) unsigned short us4;
typedef __attribute__((ext_vector_type(8))) unsigned short us8;

#define B_   32
#define C_   1536
#define CI_  768
#define N_   784
#define S_   196
#define MP_  224
#define MK_  196

__device__ __forceinline__ unsigned short f2h(float f) {
    _Float16 h = (_Float16)f;      // v_cvt_f16_f32, RTNE
    return __builtin_bit_cast(unsigned short, h);
}
__device__ __forceinline__ f32x4 mfma_f16(f16x8 a, f16x8 b, f32x4 c) {
    return __builtin_amdgcn_mfma_f32_16x16x32_f16(a, b, c, 0, 0, 0);
}

// ---------------------------------------------------------------------------
// Kernel 0: x fp32 (b4, c, 14, 14) -> xjT fp16 (b, n=784, c) via LDS transpose
// ---------------------------------------------------------------------------
__global__ __launch_bounds__(256) void k_build_xjT(const float* __restrict__ x,
                                                   unsigned short* __restrict__ xjT) {
    __shared__ __align__(16) unsigned short lds[196 * 40];
    int c0 = blockIdx.x * 32;      // 48 c-tiles
    int b4 = blockIdx.y;           // 128 images
    int b = b4 >> 2, v = b4 & 3;
    int tid = threadIdx.x;
    const float* src = x + ((size_t)b4 * C_ + c0) * S_;
    for (int idx = tid; idx < 32 * 49; idx += 256) {
        int cl = idx / 49;
        int sq = idx - cl * 49;
        f32x4 val = *(const f32x4*)(src + (size_t)cl * S_ + sq * 4);
        int s = sq * 4;
        lds[(s + 0) * 40 + cl] = f2h(val[0]);
        lds[(s + 1) * 40 + cl] = f2h(val[1]);
        lds[(s + 2) * 40 + cl] = f2h(val[2]);
        lds[(s + 3) * 40 + cl] = f2h(val[3]);
    }
    __syncthreads();
    int rowbase = (v >> 1) * 14, colbase = (v & 1) * 14;
    for (int idx = tid; idx < 196 * 4; idx += 256) {
        int s = idx >> 2, ch = idx & 3;
        int hh = s / 14, ww = s - hh * 14;
        int n = (rowbase + hh) * 28 + colbase + ww;
        us8 val = *(const us8*)(&lds[s * 40 + ch * 8]);
        *(us8*)(xjT + ((size_t)b * N_ + n) * C_ + c0 + ch * 8) = val;
    }
}

// ---------------------------------------------------------------------------
// BN constant prep (all fp32): scale = gamma*rsqrt(var+eps);
// shift = (b_W - mean)*scale + beta
// ---------------------------------------------------------------------------
__global__ __launch_bounds__(256) void k_bnprep(const float* __restrict__ bw,
                                                const float* __restrict__ gamma,
                                                const float* __restrict__ beta,
                                                const float* __restrict__ mean,
                                                const float* __restrict__ var,
                                                float* __restrict__ scale,
                                                float* __restrict__ shift) {
    int i = blockIdx.x * 256 + threadIdx.x;
    if (i < C_) {
        float sc = gamma[i] * rsqrtf(var[i] + 1e-5f);
        scale[i] = sc;
        shift[i] = (bw[i] - mean[i]) * sc + beta[i];
    }
}

// ---------------------------------------------------------------------------
// Kernel 1: fused conv3 GEMM.  out[o,n] = bias[o] + sum_c W[o,c]*xjT[n,c]
// M=2304 (theta | phi | g), N=784, K=1536, per batch b.  Tile 128(o) x 112(n).
// A staged fp32->fp16 inline; B staged us8 from fp16 xjT.
// Epilogue: theta -> theta_T (b,n,ci); phi -> pool+transpose (b,m,ci);
//           g -> pool (b,ci,m).  maxpool commutes with +bias.
// ---------------------------------------------------------------------------
__global__ __launch_bounds__(256) void k_conv3(
    const unsigned short* __restrict__ xjT,
    const float* __restrict__ w_theta, const float* __restrict__ b_theta,
    const float* __restrict__ w_phi,   const float* __restrict__ b_phi,
    const float* __restrict__ w_g,     const float* __restrict__ b_g,
    unsigned short* __restrict__ theta_T, unsigned short* __restrict__ phi_p,
    unsigned short* __restrict__ g_p) {
    __shared__ __align__(16) unsigned char smem[28672];
    unsigned short* A_s = (unsigned short*)smem;   // 128 x 40 (pad)
    unsigned short* B_s = A_s + 128 * 40;          // 112 x 40
    float* fLDS = (float*)smem;                    // 64 x 112 (epilogue reuse)

    int tn = blockIdx.x;            // 0..6
    int tm = blockIdx.y;            // 0..17
    int b  = blockIdx.z;
    int o0 = tm * 128, n0 = tn * 112;
    int region = o0 / 768;          // 0 theta, 1 phi, 2 g (tiles never straddle)
    int obase = o0 - region * 768;
    const float* W    = (region == 0) ? w_theta : (region == 1) ? w_phi : w_g;
    const float* bias = (region == 0) ? b_theta : (region == 1) ? b_phi : b_g;

    int tid = threadIdx.x;
    int wv = tid >> 6, lane = tid & 63, lr = lane & 15, quad = lane >> 4;

    f32x4 acc[2][7];
#pragma unroll
    for (int i = 0; i < 2; ++i)
#pragma unroll
        for (int j = 0; j < 7; ++j) acc[i][j] = (f32x4){0.f, 0.f, 0.f, 0.f};

    const float* Arow = W + (size_t)obase * C_;
    const unsigned short* Brow = xjT + ((size_t)b * N_ + n0) * C_;

    for (int kk = 0; kk < 48; ++kk) {
        int k0 = kk * 32;
        {   // stage A: 128 rows x 8 float4 = 1024 units => 4/thread, cvt to fp16
            int idx = tid;
#pragma unroll
            for (int p = 0; p < 4; ++p, idx += 256) {
                int row = idx >> 3, ch = idx & 7;
                f32x4 v = *(const f32x4*)(Arow + (size_t)row * C_ + k0 + ch * 4);
                us4 o;
                o[0] = f2h(v[0]); o[1] = f2h(v[1]);
                o[2] = f2h(v[2]); o[3] = f2h(v[3]);
                *(us4*)(&A_s[row * 40 + ch * 4]) = o;
            }
        }
        for (int idx = tid; idx < 448; idx += 256) {   // stage B: 112 x 4 us8
            int row = idx >> 2, ch = idx & 3;
            *(us8*)(&B_s[row * 40 + ch * 8]) =
                *(const us8*)(Brow + (size_t)row * C_ + k0 + ch * 8);
        }
        __syncthreads();
        f16x8 a0 = *(const f16x8*)(&A_s[((2 * wv + 0) * 16 + lr) * 40 + quad * 8]);
        f16x8 a1 = *(const f16x8*)(&A_s[((2 * wv + 1) * 16 + lr) * 40 + quad * 8]);
#pragma unroll
        for (int j = 0; j < 7; ++j) {
            f16x8 bb = *(const f16x8*)(&B_s[(j * 16 + lr) * 40 + quad * 8]);
            acc[0][j] = mfma_f16(a0, bb, acc[0][j]);
            acc[1][j] = mfma_f16(a1, bb, acc[1][j]);
        }
        __syncthreads();
    }

    // Epilogue: two 64-row halves through fLDS
    for (int h = 0; h < 2; ++h) {
        if ((wv >> 1) == h) {
            int wrel = wv & 1;
#pragma unroll
            for (int i = 0; i < 2; ++i)
#pragma unroll
                for (int j = 0; j < 7; ++j)
#pragma unroll
                    for (int r = 0; r < 4; ++r) {
                        int o_rel = (wrel * 2 + i) * 16 + quad * 4 + r;   // 0..63
                        int n_l = j * 16 + lr;
                        fLDS[o_rel * 112 + n_l] = acc[i][j][r];
                    }
        }
        __syncthreads();
        if (region == 0) {
            // theta: write transposed (b, n, ci), coalesced over ci
            for (int idx = tid; idx < 112 * 8; idx += 256) {
                int n_l = idx >> 3, ch = idx & 7;
                us8 outv;
#pragma unroll
                for (int k = 0; k < 8; ++k) {
                    int o_rel = ch * 8 + k;
                    float val = fLDS[o_rel * 112 + n_l] + bias[obase + h * 64 + o_rel];
                    outv[k] = f2h(val);
                }
                *(us8*)(theta_T + ((size_t)b * N_ + n0 + n_l) * CI_ + o0 + h * 64 + ch * 8) = outv;
            }
        } else if (region == 1) {
            // phi: 2x2 maxpool + transpose -> (b, m, ci)
            for (int idx = tid; idx < 28 * 8; idx += 256) {
                int mm = idx >> 3, ch = idx & 7;
                int a = mm / 14, mw = mm - a * 14;
                int m = (tn * 2 + a) * 14 + mw;
                int sb = a * 56 + mw * 2;
                us8 outv;
#pragma unroll
                for (int k = 0; k < 8; ++k) {
                    int o_rel = ch * 8 + k;
                    const float* p = &fLDS[o_rel * 112 + sb];
                    float val = fmaxf(fmaxf(p[0], p[1]), fmaxf(p[28], p[29]));
                    val += bias[obase + h * 64 + o_rel];
                    outv[k] = f2h(val);
                }
                *(us8*)(phi_p + ((size_t)b * MP_ + m) * CI_ + obase + h * 64 + ch * 8) = outv;
            }
        } else {
            // g: 2x2 maxpool -> (b, ci, m)
            for (int idx = tid; idx < 128; idx += 256) {
                int o_rel = idx >> 1, a = idx & 1;
                int ci = obase + h * 64 + o_rel;
                unsigned short* dst = g_p + ((size_t)b * CI_ + ci) * MP_ + (tn * 2 + a) * 14;
                const float* p0 = &fLDS[o_rel * 112 + a * 56];
                float bv = bias[obase + h * 64 + o_rel];
#pragma unroll
                for (int mw = 0; mw < 14; ++mw) {
                    const float* p = p0 + mw * 2;
                    dst[mw] = f2h(fmaxf(fmaxf(p[0], p[1]), fmaxf(p[28], p[29])) + bv);
                }
            }
        }
        __syncthreads();
    }
}

// ---------------------------------------------------------------------------
// Kernel 2: fused attention per (b, 32-query tile).  All fp16 intermediates.
// f = theta_T @ phi_p^T (K=768) -> LDS -> softmax(196) -> y = attn @ g_p^T
// ---------------------------------------------------------------------------
__global__ __launch_bounds__(256) void k_attn(
    const unsigned short* __restrict__ theta_T,
    const unsigned short* __restrict__ phi_p,
    const unsigned short* __restrict__ g_p,
    unsigned short* __restrict__ y) {
    __shared__ __align__(16) unsigned char smem[23040 + 32 * 228 * 4];
    unsigned short* A_s = (unsigned short*)smem;   // 32 x 40
    unsigned short* B_s = A_s + 32 * 40;           // 224 x 40
    unsigned short* G_s = (unsigned short*)smem;   // phase2: 256 x 40 (reuse)
    float* f_s = (float*)(smem + 23040);           // 32 x 228

    int nb = blockIdx.x, b = blockIdx.y;
    int n0 = nb * 32;
    int tid = threadIdx.x, wv = tid >> 6, lane = tid & 63, lr = lane & 15, quad = lane >> 4;
    int mf0 = wv * 4;
    int nm = (mf0 + 4 <= 14) ? 4 : (14 - mf0);     // 4,4,4,2

    f32x4 acc[2][4];
#pragma unroll
    for (int i = 0; i < 2; ++i)
#pragma unroll
        for (int j = 0; j < 4; ++j) acc[i][j] = (f32x4){0.f, 0.f, 0.f, 0.f};

    for (int kk = 0; kk < 24; ++kk) {
        int k0 = kk * 32;
        if (tid < 128) {                            // stage A: 32 rows x 4
            int row = tid >> 2, ch = tid & 3;
            int n = n0 + row;
            us8 v = {0, 0, 0, 0, 0, 0, 0, 0};
            if (n < N_) v = *(const us8*)(theta_T + ((size_t)b * N_ + n) * CI_ + k0 + ch * 8);
            *(us8*)(&A_s[row * 40 + ch * 8]) = v;
        }
        for (int idx = tid; idx < 896; idx += 256) { // stage B: 224 rows x 4
            int row = idx >> 2, ch = idx & 3;
            *(us8*)(&B_s[row * 40 + ch * 8]) =
                *(const us8*)(phi_p + ((size_t)b * MP_ + row) * CI_ + k0 + ch * 8);
        }
        __syncthreads();
        f16x8 a0 = *(const f16x8*)(&A_s[(0 * 16 + lr) * 40 + quad * 8]);
        f16x8 a1 = *(const f16x8*)(&A_s[(1 * 16 + lr) * 40 + quad * 8]);
        for (int j = 0; j < nm; ++j) {
            f16x8 bb = *(const f16x8*)(&B_s[((mf0 + j) * 16 + lr) * 40 + quad * 8]);
            acc[0][j] = mfma_f16(a0, bb, acc[0][j]);
            acc[1][j] = mfma_f16(a1, bb, acc[1][j]);
        }
        __syncthreads();
    }
    // dump f to LDS (fp32)
    for (int i = 0; i < 2; ++i)
        for (int j = 0; j < nm; ++j)
#pragma unroll
            for (int r = 0; r < 4; ++r)
                f_s[(i * 16 + quad * 4 + r) * 228 + (mf0 + j) * 16 + lr] = acc[i][j][r];
    __syncthreads();
    // softmax per query row over 196 real keys; zero the 28 pad keys
    if (tid < 32) {
        float* row = f_s + tid * 228;
        float mx = -1e30f;
        for (int m = 0; m < MK_; ++m) mx = fmaxf(mx, row[m]);
        float sum = 0.f;
        for (int m = 0; m < MK_; ++m) { float e = __expf(row[m] - mx); row[m] = e; sum += e; }
        float inv = 1.0f / sum;
        for (int m = 0; m < MK_; ++m) row[m] *= inv;
        for (int m = MK_; m < MP_; ++m) row[m] = 0.f;
    }
    __syncthreads();
    // phase 2: y[n, ci] = sum_m attn[n,m] * g_p[ci,m], ci chunks of 256
    for (int c3 = 0; c3 < 3; ++c3) {
        int ci0 = c3 * 256;
        f32x4 acc2[2][4];
#pragma unroll
        for (int i = 0; i < 2; ++i)
#pragma unroll
            for (int j = 0; j < 4; ++j) acc2[i][j] = (f32x4){0.f, 0.f, 0.f, 0.f};
        for (int km = 0; km < 7; ++km) {
            int k0 = km * 32;
            {
                int idx = tid;
#pragma unroll
                for (int p = 0; p < 4; ++p, idx += 256) {   // 256 rows x 4
                    int row = idx >> 2, ch = idx & 3;
                    *(us8*)(&G_s[row * 40 + ch * 8]) =
                        *(const us8*)(g_p + ((size_t)b * CI_ + ci0 + row) * MP_ + k0 + ch * 8);
                }
            }
            __syncthreads();
            f16x8 a[2];
#pragma unroll
            for (int i = 0; i < 2; ++i) {
                const float* fp = &f_s[(i * 16 + lr) * 228 + k0 + quad * 8];
                f16x8 t;
#pragma unroll
                for (int j = 0; j < 8; ++j) t[j] = (_Float16)fp[j];
                a[i] = t;
            }
#pragma unroll
            for (int j = 0; j < 4; ++j) {
                f16x8 bb = *(const f16x8*)(&G_s[((wv * 4 + j) * 16 + lr) * 40 + quad * 8]);
                acc2[0][j] = mfma_f16(a[0], bb, acc2[0][j]);
                acc2[1][j] = mfma_f16(a[1], bb, acc2[1][j]);
            }
            __syncthreads();
        }
#pragma unroll
        for (int i = 0; i < 2; ++i)
#pragma unroll
            for (int j = 0; j < 4; ++j)
#pragma unroll
                for (int r = 0; r < 4; ++r) {
                    int n = n0 + i * 16 + quad * 4 + r;
                    if (n < N_) {
                        int ci = ci0 + (wv * 4 + j) * 16 + lr;
                        y[((size_t)b * N_ + n) * CI_ + ci] = f2h(acc2[i][j][r]);
                    }
                }
    }
}

// ---------------------------------------------------------------------------
// Kernel 3: out = BN(wW @ y) + xj.  M=1536, N=784, K=768 per batch.
// A = wW fp32 (cvt inline); B = yb fp16; residual from fp32 x; out fp32.
// ---------------------------------------------------------------------------
__global__ __launch_bounds__(256) void k_final(
    const unsigned short* __restrict__ yb,
    const float* __restrict__ wW,
    const float* __restrict__ scale, const float* __restrict__ shift,
    const float* __restrict__ x,
    float* __restrict__ out) {
    __shared__ __align__(16) unsigned short smem_us[9600];
    unsigned short* A_s = smem_us;            // 128 x 40
    unsigned short* B_s = smem_us + 128 * 40; // 112 x 40
    int tn = blockIdx.x, tm = blockIdx.y, b = blockIdx.z;
    int o0 = tm * 128, n0 = tn * 112;
    int tid = threadIdx.x, wv = tid >> 6, lane = tid & 63, lr = lane & 15, quad = lane >> 4;

    f32x4 acc[2][7];
#pragma unroll
    for (int i = 0; i < 2; ++i)
#pragma unroll
        for (int j = 0; j < 7; ++j) acc[i][j] = (f32x4){0.f, 0.f, 0.f, 0.f};

    const float* Arow = wW + (size_t)o0 * CI_;
    const unsigned short* Brow = yb + ((size_t)b * N_ + n0) * CI_;

    for (int kk = 0; kk < 24; ++kk) {
        int k0 = kk * 32;
        {   // stage A: fp32 wW -> fp16, 1024 float4 units => 4/thread
            int idx = tid;
#pragma unroll
            for (int p = 0; p < 4; ++p, idx += 256) {
                int row = idx >> 3, ch = idx & 7;
                f32x4 v = *(const f32x4*)(Arow + (size_t)row * CI_ + k0 + ch * 4);
                us4 o;
                o[0] = f2h(v[0]); o[1] = f2h(v[1]);
                o[2] = f2h(v[2]); o[3] = f2h(v[3]);
                *(us4*)(&A_s[row * 40 + ch * 4]) = o;
            }
        }
        for (int idx = tid; idx < 448; idx += 256) {
            int row = idx >> 2, ch = idx & 3;
            *(us8*)(&B_s[row * 40 + ch * 8]) =
                *(const us8*)(Brow + (size_t)row * CI_ + k0 + ch * 8);
        }
        __syncthreads();
        f16x8 a0 = *(const f16x8*)(&A_s[((2 * wv + 0) * 16 + lr) * 40 + quad * 8]);
        f16x8 a1 = *(const f16x8*)(&A_s[((2 * wv + 1) * 16 + lr) * 40 + quad * 8]);
#pragma unroll
        for (int j = 0; j < 7; ++j) {
            f16x8 bb = *(const f16x8*)(&B_s[(j * 16 + lr) * 40 + quad * 8]);
            acc[0][j] = mfma_f16(a0, bb, acc[0][j]);
            acc[1][j] = mfma_f16(a1, bb, acc[1][j]);
        }
        __syncthreads();
    }
#pragma unroll
    for (int i = 0; i < 2; ++i)
#pragma unroll
        for (int r = 0; r < 4; ++r) {
            int o = o0 + (2 * wv + i) * 16 + quad * 4 + r;
            float sc = scale[o], sh = shift[o];
#pragma unroll
            for (int j = 0; j < 7; ++j) {
                int n = n0 + j * 16 + lr;
                int hh = n / 28, ww = n - hh * 28;
                int vv = ((hh >= 14) ? 2 : 0) + ((ww >= 14) ? 1 : 0);
                int s = (hh - ((hh >= 14) ? 14 : 0)) * 14 + (ww - ((ww >= 14) ? 14 : 0));
                float xval = x[((size_t)(b * 4 + vv) * C_ + o) * S_ + s];
                out[((size_t)b * C_ + o) * N_ + n] = acc[i][j][r] * sc + sh + xval;
            }
        }
}

// ---------------------------------------------------------------------------
extern "C" void kernel_launch(void* const* d_in, const int* in_sizes, int n_in,
                              void* d_out, int out_size, void* d_ws, size_t ws_size,
                              hipStream_t stream) {
    (void)in_sizes; (void)n_in; (void)out_size; (void)ws_size;
    const float* x       = (const float*)d_in[0];
    const float* w_theta = (const float*)d_in[1];
    const float* b_theta = (const float*)d_in[2];
    const float* w_phi   = (const float*)d_in[3];
    const float* b_phi   = (const float*)d_in[4];
    const float* w_g     = (const float*)d_in[5];
    const float* b_g     = (const float*)d_in[6];
    const float* w_W     = (const float*)d_in[7];
    const float* b_W     = (const float*)d_in[8];
    const float* gamma   = (const float*)d_in[9];
    const float* beta    = (const float*)d_in[10];
    const float* mean    = (const float*)d_in[11];
    const float* var     = (const float*)d_in[12];

    // d_out (154,140,672 B fp32) doubles as scratch for everything dead
    // before k_final writes it:
    char* ob = (char*)d_out;
    unsigned short* xjT     = (unsigned short*)(ob);              //  77,070,336 B
    unsigned short* theta_T = (unsigned short*)(ob + 77070336);   //  38,535,168 B
    unsigned short* phi_p   = (unsigned short*)(ob + 115605504);  //  11,010,048 B
    unsigned short* g_p     = (unsigned short*)(ob + 126615552);  //  11,010,048 B -> ends 137,625,600

    // d_ws: only yb (must survive into k_final) + BN constants = 38.5 MB
    char* ws = (char*)d_ws;
    unsigned short* yb    = (unsigned short*)(ws);                //  38,535,168 B
    float*          scale = (float*)(ws + 38535168);              //  6,144 B
    float*          shift = (float*)(ws + 38541312);              //  6,144 B

    // zero pooled buffers so the m=196..223 key padding is exactly 0
    hipMemsetAsync(phi_p, 0, 11010048, stream);
    hipMemsetAsync(g_p, 0, 11010048, stream);

    k_bnprep<<<6, 256, 0, stream>>>(b_W, gamma, beta, mean, var, scale, shift);
    k_build_xjT<<<dim3(48, 128), 256, 0, stream>>>(x, xjT);
    k_conv3<<<dim3(7, 18, 32), 256, 0, stream>>>(xjT, w_theta, b_theta, w_phi, b_phi,
                                                 w_g, b_g, theta_T, phi_p, g_p);
    k_attn<<<dim3(25, 32), 256, 0, stream>>>(theta_T, phi_p, g_p, yb);
    k_final<<<dim3(7, 12, 32), 256, 0, stream>>>(yb, w_W, scale, shift, x,
                                                 (float*)d_out);
}

// Round 5
// 888.853 us; speedup vs baseline: 1.2003x; 1.2003x over previous
//
#include <hip/hip_runtime.h>
#include <hip/hip_bf16.h>

typedef __attribute__((ext_vector_type(8))) _Float16 f16x8;
typedef __attribute__((ext_vector_type(4))) float f32x4;
typedef __attribute__((ext_vector_type(4))) unsigned short us4;
typedef __attribute__((ext_vector_type(8))) unsigned short us8;

#define B_   32
#define C_   1536
#define CI_  768
#define N_   784
#define S_   196
#define MP_  224
#define MK_  196

__device__ __forceinline__ unsigned short f2h(float f) {
    _Float16 h = (_Float16)f;      // v_cvt_f16_f32, RTNE
    return __builtin_bit_cast(unsigned short, h);
}
__device__ __forceinline__ f32x4 mfma_f16(f16x8 a, f16x8 b, f32x4 c) {
    return __builtin_amdgcn_mfma_f32_16x16x32_f16(a, b, c, 0, 0, 0);
}
// async 16B global->LDS: per-lane global addr, wave-uniform LDS base;
// HW writes lane l's 16B to base + l*16 (layouts below are lane-ordered).
__device__ __forceinline__ void gl_lds16(const unsigned short* g, unsigned short* l) {
    __builtin_amdgcn_global_load_lds(
        (const __attribute__((address_space(1))) unsigned int*)g,
        (__attribute__((address_space(3))) unsigned int*)l, 16, 0, 0);
}

// ---------------------------------------------------------------------------
// fp32 -> fp16 weight pre-convert (count4 = #float4 units)
// ---------------------------------------------------------------------------
__global__ __launch_bounds__(256) void k_cvt(const float* __restrict__ src,
                                             unsigned short* __restrict__ dst,
                                             int count4) {
    int idx = blockIdx.x * 256 + threadIdx.x;
    if (idx < count4) {
        f32x4 v = ((const f32x4*)src)[idx];
        us4 o;
        o[0] = f2h(v[0]); o[1] = f2h(v[1]); o[2] = f2h(v[2]); o[3] = f2h(v[3]);
        ((us4*)dst)[idx] = o;
    }
}

// ---------------------------------------------------------------------------
// Kernel 0: x fp32 (b4, c, 14, 14) -> xjT fp16 (b, n=784, c) via LDS transpose
// ---------------------------------------------------------------------------
__global__ __launch_bounds__(256) void k_build_xjT(const float* __restrict__ x,
                                                   unsigned short* __restrict__ xjT) {
    __shared__ __align__(16) unsigned short lds[196 * 40];
    int c0 = blockIdx.x * 32;      // 48 c-tiles
    int b4 = blockIdx.y;           // 128 images
    int b = b4 >> 2, v = b4 & 3;
    int tid = threadIdx.x;
    const float* src = x + ((size_t)b4 * C_ + c0) * S_;
    for (int idx = tid; idx < 32 * 49; idx += 256) {
        int cl = idx / 49;
        int sq = idx - cl * 49;
        f32x4 val = *(const f32x4*)(src + (size_t)cl * S_ + sq * 4);
        int s = sq * 4;
        lds[(s + 0) * 40 + cl] = f2h(val[0]);
        lds[(s + 1) * 40 + cl] = f2h(val[1]);
        lds[(s + 2) * 40 + cl] = f2h(val[2]);
        lds[(s + 3) * 40 + cl] = f2h(val[3]);
    }
    __syncthreads();
    int rowbase = (v >> 1) * 14, colbase = (v & 1) * 14;
    for (int idx = tid; idx < 196 * 4; idx += 256) {
        int s = idx >> 2, ch = idx & 3;
        int hh = s / 14, ww = s - hh * 14;
        int n = (rowbase + hh) * 28 + colbase + ww;
        us8 val = *(const us8*)(&lds[s * 40 + ch * 8]);
        *(us8*)(xjT + ((size_t)b * N_ + n) * C_ + c0 + ch * 8) = val;
    }
}

// ---------------------------------------------------------------------------
// BN constant prep
// ---------------------------------------------------------------------------
__global__ __launch_bounds__(256) void k_bnprep(const float* __restrict__ bw,
                                                const float* __restrict__ gamma,
                                                const float* __restrict__ beta,
                                                const float* __restrict__ mean,
                                                const float* __restrict__ var,
                                                float* __restrict__ scale,
                                                float* __restrict__ shift) {
    int i = blockIdx.x * 256 + threadIdx.x;
    if (i < C_) {
        float sc = gamma[i] * rsqrtf(var[i] + 1e-5f);
        scale[i] = sc;
        shift[i] = (bw[i] - mean[i]) * sc + beta[i];
    }
}

// ---------------------------------------------------------------------------
// Kernel 1: fused conv3 GEMM.  out[o,n] = bias[o] + sum_c wf[o,c]*xjT[n,c]
// M=2304 stacked fp16 weights, N=784, K=1536, per b.  Tile 128(o) x 112(n).
// Staging: global_load_lds 16B, unpadded 64B rows (lane-ordered chunks).
// ---------------------------------------------------------------------------
__global__ __launch_bounds__(256) void k_conv3(
    const unsigned short* __restrict__ xjT,
    const unsigned short* __restrict__ wf,      // (2304, 1536) fp16 stacked
    const float* __restrict__ b_theta, const float* __restrict__ b_phi,
    const float* __restrict__ b_g,
    unsigned short* __restrict__ theta_T, unsigned short* __restrict__ phi_p,
    unsigned short* __restrict__ g_p) {
    __shared__ __align__(16) unsigned char smem[28672];
    unsigned short* A_s = (unsigned short*)smem;   // 128 x 32 (64B rows)
    unsigned short* B_s = A_s + 128 * 32;          // 112 x 32
    float* fLDS = (float*)smem;                    // 64 x 112 (epilogue reuse)

    int tn = blockIdx.x;            // 0..6
    int tm = blockIdx.y;            // 0..17
    int b  = blockIdx.z;
    int o0 = tm * 128, n0 = tn * 112;
    int region = o0 / 768;          // 0 theta, 1 phi, 2 g
    int obase = o0 - region * 768;
    const float* bias = (region == 0) ? b_theta : (region == 1) ? b_phi : b_g;

    int tid = threadIdx.x;
    int wv = tid >> 6, lane = tid & 63, lr = lane & 15, quad = lane >> 4;
    int l4r = lane >> 2, l4c = lane & 3;   // DMA chunk: 16 rows x 4 x 16B

    f32x4 acc[2][7];
#pragma unroll
    for (int i = 0; i < 2; ++i)
#pragma unroll
        for (int j = 0; j < 7; ++j) acc[i][j] = (f32x4){0.f, 0.f, 0.f, 0.f};

    const unsigned short* Arow = wf + (size_t)o0 * C_;
    const unsigned short* Brow = xjT + ((size_t)b * N_ + n0) * C_;

    for (int kk = 0; kk < 48; ++kk) {
        int k0 = kk * 32;
        // stage: 15 chunks of 1KB (A: 8, B: 7), DMA'd by wave c%4
        for (int c = wv; c < 15; c += 4) {
            if (c < 8) {
                int row = c * 16 + l4r;
                gl_lds16(Arow + (size_t)row * C_ + k0 + l4c * 8, A_s + c * 512);
            } else {
                int cb = c - 8;
                int row = cb * 16 + l4r;
                gl_lds16(Brow + (size_t)row * C_ + k0 + l4c * 8, B_s + cb * 512);
            }
        }
        __syncthreads();
        f16x8 a0 = *(const f16x8*)(&A_s[((2 * wv + 0) * 16 + lr) * 32 + quad * 8]);
        f16x8 a1 = *(const f16x8*)(&A_s[((2 * wv + 1) * 16 + lr) * 32 + quad * 8]);
#pragma unroll
        for (int j = 0; j < 7; ++j) {
            f16x8 bb = *(const f16x8*)(&B_s[(j * 16 + lr) * 32 + quad * 8]);
            acc[0][j] = mfma_f16(a0, bb, acc[0][j]);
            acc[1][j] = mfma_f16(a1, bb, acc[1][j]);
        }
        __syncthreads();
    }

    // Epilogue: two 64-row halves through fLDS
    for (int h = 0; h < 2; ++h) {
        if ((wv >> 1) == h) {
            int wrel = wv & 1;
#pragma unroll
            for (int i = 0; i < 2; ++i)
#pragma unroll
                for (int j = 0; j < 7; ++j)
#pragma unroll
                    for (int r = 0; r < 4; ++r) {
                        int o_rel = (wrel * 2 + i) * 16 + quad * 4 + r;   // 0..63
                        int n_l = j * 16 + lr;
                        fLDS[o_rel * 112 + n_l] = acc[i][j][r];
                    }
        }
        __syncthreads();
        if (region == 0) {
            for (int idx = tid; idx < 112 * 8; idx += 256) {
                int n_l = idx >> 3, ch = idx & 7;
                us8 outv;
#pragma unroll
                for (int k = 0; k < 8; ++k) {
                    int o_rel = ch * 8 + k;
                    float val = fLDS[o_rel * 112 + n_l] + bias[obase + h * 64 + o_rel];
                    outv[k] = f2h(val);
                }
                *(us8*)(theta_T + ((size_t)b * N_ + n0 + n_l) * CI_ + o0 + h * 64 + ch * 8) = outv;
            }
        } else if (region == 1) {
            for (int idx = tid; idx < 28 * 8; idx += 256) {
                int mm = idx >> 3, ch = idx & 7;
                int a = mm / 14, mw = mm - a * 14;
                int m = (tn * 2 + a) * 14 + mw;
                int sb = a * 56 + mw * 2;
                us8 outv;
#pragma unroll
                for (int k = 0; k < 8; ++k) {
                    int o_rel = ch * 8 + k;
                    const float* p = &fLDS[o_rel * 112 + sb];
                    float val = fmaxf(fmaxf(p[0], p[1]), fmaxf(p[28], p[29]));
                    val += bias[obase + h * 64 + o_rel];
                    outv[k] = f2h(val);
                }
                *(us8*)(phi_p + ((size_t)b * MP_ + m) * CI_ + obase + h * 64 + ch * 8) = outv;
            }
        } else {
            for (int idx = tid; idx < 128; idx += 256) {
                int o_rel = idx >> 1, a = idx & 1;
                int ci = obase + h * 64 + o_rel;
                unsigned short* dst = g_p + ((size_t)b * CI_ + ci) * MP_ + (tn * 2 + a) * 14;
                const float* p0 = &fLDS[o_rel * 112 + a * 56];
                float bv = bias[obase + h * 64 + o_rel];
#pragma unroll
                for (int mw = 0; mw < 14; ++mw) {
                    const float* p = p0 + mw * 2;
                    dst[mw] = f2h(fmaxf(fmaxf(p[0], p[1]), fmaxf(p[28], p[29])) + bv);
                }
            }
        }
        __syncthreads();
    }
}

// ---------------------------------------------------------------------------
// Kernel 2: fused attention per (b, 32-query tile).  Register GEMM straight
// from global (theta_T/phi_p/g_p all K-contiguous us8 frags).  Barriers only
// around the softmax.
// ---------------------------------------------------------------------------
__global__ __launch_bounds__(256) void k_attn(
    const unsigned short* __restrict__ theta_T,
    const unsigned short* __restrict__ phi_p,
    const unsigned short* __restrict__ g_p,
    unsigned short* __restrict__ y) {
    __shared__ __align__(16) float f_s[32 * 228];

    int nb = blockIdx.x, b = blockIdx.y;
    int n0 = nb * 32;
    int tid = threadIdx.x, wv = tid >> 6, lane = tid & 63, lr = lane & 15, quad = lane >> 4;
    int mf0 = wv * 4;
    int nm = (mf0 + 4 <= 14) ? 4 : (14 - mf0);     // frags of keys: 4,4,4,2

    // A rows (queries), clamped for the last tile (rows >= 784 discarded later)
    int na0 = n0 + lr;       if (na0 > 783) na0 = 783;
    int na1 = n0 + 16 + lr;  if (na1 > 783) na1 = 783;
    const unsigned short* tA0 = theta_T + ((size_t)b * N_ + na0) * CI_ + quad * 8;
    const unsigned short* tA1 = theta_T + ((size_t)b * N_ + na1) * CI_ + quad * 8;

    f32x4 acc[2][4];
#pragma unroll
    for (int i = 0; i < 2; ++i)
#pragma unroll
        for (int j = 0; j < 4; ++j) acc[i][j] = (f32x4){0.f, 0.f, 0.f, 0.f};

    for (int kk = 0; kk < 24; ++kk) {
        int k0 = kk * 32;
        f16x8 a0 = *(const f16x8*)(tA0 + k0);
        f16x8 a1 = *(const f16x8*)(tA1 + k0);
        for (int j = 0; j < nm; ++j) {
            f16x8 bb = *(const f16x8*)(phi_p +
                ((size_t)b * MP_ + (mf0 + j) * 16 + lr) * CI_ + k0 + quad * 8);
            acc[0][j] = mfma_f16(a0, bb, acc[0][j]);
            acc[1][j] = mfma_f16(a1, bb, acc[1][j]);
        }
    }
    // dump f to LDS (fp32)
    for (int i = 0; i < 2; ++i)
        for (int j = 0; j < nm; ++j)
#pragma unroll
            for (int r = 0; r < 4; ++r)
                f_s[(i * 16 + quad * 4 + r) * 228 + (mf0 + j) * 16 + lr] = acc[i][j][r];
    __syncthreads();
    // softmax per query row over 196 real keys; zero the 28 pad keys
    if (tid < 32) {
        float* row = f_s + tid * 228;
        float mx = -1e30f;
        for (int m = 0; m < MK_; ++m) mx = fmaxf(mx, row[m]);
        float sum = 0.f;
        for (int m = 0; m < MK_; ++m) { float e = __expf(row[m] - mx); row[m] = e; sum += e; }
        float inv = 1.0f / sum;
        for (int m = 0; m < MK_; ++m) row[m] *= inv;
        for (int m = MK_; m < MP_; ++m) row[m] = 0.f;
    }
    __syncthreads();
    // phase 2: y[n, ci] = sum_m attn[n,m] * g_p[ci,m]; B-frags direct global
    for (int c3 = 0; c3 < 3; ++c3) {
        int ci0 = c3 * 256;
        f32x4 acc2[2][4];
#pragma unroll
        for (int i = 0; i < 2; ++i)
#pragma unroll
            for (int j = 0; j < 4; ++j) acc2[i][j] = (f32x4){0.f, 0.f, 0.f, 0.f};
        for (int km = 0; km < 7; ++km) {
            int k0 = km * 32;
            f16x8 a[2];
#pragma unroll
            for (int i = 0; i < 2; ++i) {
                const float* fp = &f_s[(i * 16 + lr) * 228 + k0 + quad * 8];
                f16x8 t;
#pragma unroll
                for (int j = 0; j < 8; ++j) t[j] = (_Float16)fp[j];
                a[i] = t;
            }
#pragma unroll
            for (int j = 0; j < 4; ++j) {
                f16x8 bb = *(const f16x8*)(g_p +
                    ((size_t)b * CI_ + ci0 + (wv * 4 + j) * 16 + lr) * MP_ + k0 + quad * 8);
                acc2[0][j] = mfma_f16(a[0], bb, acc2[0][j]);
                acc2[1][j] = mfma_f16(a[1], bb, acc2[1][j]);
            }
        }
#pragma unroll
        for (int i = 0; i < 2; ++i)
#pragma unroll
            for (int j = 0; j < 4; ++j)
#pragma unroll
                for (int r = 0; r < 4; ++r) {
                    int n = n0 + i * 16 + quad * 4 + r;
                    if (n < N_) {
                        int ci = ci0 + (wv * 4 + j) * 16 + lr;
                        y[((size_t)b * N_ + n) * CI_ + ci] = f2h(acc2[i][j][r]);
                    }
                }
    }
}

// ---------------------------------------------------------------------------
// Kernel 3: out = BN(wfW @ y) + xj.  M=1536, N=784, K=768 per batch.
// Staging via global_load_lds 16B, unpadded 64B rows.
// ---------------------------------------------------------------------------
__global__ __launch_bounds__(256) void k_final(
    const unsigned short* __restrict__ yb,
    const unsigned short* __restrict__ wfW,     // (1536, 768) fp16
    const float* __restrict__ scale, const float* __restrict__ shift,
    const float* __restrict__ x,
    float* __restrict__ out) {
    __shared__ __align__(16) unsigned short smem_us[128 * 32 + 112 * 32];
    unsigned short* A_s = smem_us;            // 128 x 32
    unsigned short* B_s = smem_us + 128 * 32; // 112 x 32
    int tn = blockIdx.x, tm = blockIdx.y, b = blockIdx.z;
    int o0 = tm * 128, n0 = tn * 112;
    int tid = threadIdx.x, wv = tid >> 6, lane = tid & 63, lr = lane & 15, quad = lane >> 4;
    int l4r = lane >> 2, l4c = lane & 3;

    f32x4 acc[2][7];
#pragma unroll
    for (int i = 0; i < 2; ++i)
#pragma unroll
        for (int j = 0; j < 7; ++j) acc[i][j] = (f32x4){0.f, 0.f, 0.f, 0.f};

    const unsigned short* Arow = wfW + (size_t)o0 * CI_;
    const unsigned short* Brow = yb + ((size_t)b * N_ + n0) * CI_;

    for (int kk = 0; kk < 24; ++kk) {
        int k0 = kk * 32;
        for (int c = wv; c < 15; c += 4) {
            if (c < 8) {
                int row = c * 16 + l4r;
                gl_lds16(Arow + (size_t)row * CI_ + k0 + l4c * 8, A_s + c * 512);
            } else {
                int cb = c - 8;
                int row = cb * 16 + l4r;
                gl_lds16(Brow + (size_t)row * CI_ + k0 + l4c * 8, B_s + cb * 512);
            }
        }
        __syncthreads();
        f16x8 a0 = *(const f16x8*)(&A_s[((2 * wv + 0) * 16 + lr) * 32 + quad * 8]);
        f16x8 a1 = *(const f16x8*)(&A_s[((2 * wv + 1) * 16 + lr) * 32 + quad * 8]);
#pragma unroll
        for (int j = 0; j < 7; ++j) {
            f16x8 bb = *(const f16x8*)(&B_s[(j * 16 + lr) * 32 + quad * 8]);
            acc[0][j] = mfma_f16(a0, bb, acc[0][j]);
            acc[1][j] = mfma_f16(a1, bb, acc[1][j]);
        }
        __syncthreads();
    }
#pragma unroll
    for (int i = 0; i < 2; ++i)
#pragma unroll
        for (int r = 0; r < 4; ++r) {
            int o = o0 + (2 * wv + i) * 16 + quad * 4 + r;
            float sc = scale[o], sh = shift[o];
#pragma unroll
            for (int j = 0; j < 7; ++j) {
                int n = n0 + j * 16 + lr;
                int hh = n / 28, ww = n - hh * 28;
                int vv = ((hh >= 14) ? 2 : 0) + ((ww >= 14) ? 1 : 0);
                int s = (hh - ((hh >= 14) ? 14 : 0)) * 14 + (ww - ((ww >= 14) ? 14 : 0));
                float xval = x[((size_t)(b * 4 + vv) * C_ + o) * S_ + s];
                out[((size_t)b * C_ + o) * N_ + n] = acc[i][j][r] * sc + sh + xval;
            }
        }
}

// ---------------------------------------------------------------------------
extern "C" void kernel_launch(void* const* d_in, const int* in_sizes, int n_in,
                              void* d_out, int out_size, void* d_ws, size_t ws_size,
                              hipStream_t stream) {
    (void)in_sizes; (void)n_in; (void)out_size; (void)ws_size;
    const float* x       = (const float*)d_in[0];
    const float* w_theta = (const float*)d_in[1];
    const float* b_theta = (const float*)d_in[2];
    const float* w_phi   = (const float*)d_in[3];
    const float* b_phi   = (const float*)d_in[4];
    const float* w_g     = (const float*)d_in[5];
    const float* b_g     = (const float*)d_in[6];
    const float* w_W     = (const float*)d_in[7];
    const float* b_W     = (const float*)d_in[8];
    const float* gamma   = (const float*)d_in[9];
    const float* beta    = (const float*)d_in[10];
    const float* mean    = (const float*)d_in[11];
    const float* var     = (const float*)d_in[12];

    // d_out (154,140,672 B fp32) as scratch for everything dead before k_final:
    char* ob = (char*)d_out;
    unsigned short* xjT     = (unsigned short*)(ob);              //  77,070,336 B
    unsigned short* theta_T = (unsigned short*)(ob + 77070336);   //  38,535,168 B
    unsigned short* phi_p   = (unsigned short*)(ob + 115605504);  //  11,010,048 B
    unsigned short* g_p     = (unsigned short*)(ob + 126615552);  //  11,010,048 B
    unsigned short* wf3     = (unsigned short*)(ob + 137625600);  //   7,077,888 B (ends 144,703,488)

    // d_ws: yb + fp16 wW + BN constants = ~40.9 MB
    char* ws = (char*)d_ws;
    unsigned short* yb    = (unsigned short*)(ws);                //  38,535,168 B
    unsigned short* wfW   = (unsigned short*)(ws + 38535168);     //   2,359,296 B
    float*          scale = (float*)(ws + 40894464);              //   6,144 B
    float*          shift = (float*)(ws + 40900608);              //   6,144 B

    // zero pooled buffers so the m=196..223 key padding is exactly 0
    hipMemsetAsync(phi_p, 0, 11010048, stream);
    hipMemsetAsync(g_p, 0, 11010048, stream);

    k_bnprep<<<6, 256, 0, stream>>>(b_W, gamma, beta, mean, var, scale, shift);
    // weight pre-convert: 768*1536/4 = 294912 units each; wW 1536*768/4
    k_cvt<<<1152, 256, 0, stream>>>(w_theta, wf3,                294912);
    k_cvt<<<1152, 256, 0, stream>>>(w_phi,   wf3 + 768 * 1536,   294912);
    k_cvt<<<1152, 256, 0, stream>>>(w_g,     wf3 + 2 * 768 * 1536, 294912);
    k_cvt<<<1152, 256, 0, stream>>>(w_W,     wfW,                294912);
    k_build_xjT<<<dim3(48, 128), 256, 0, stream>>>(x, xjT);
    k_conv3<<<dim3(7, 18, 32), 256, 0, stream>>>(xjT, wf3, b_theta, b_phi, b_g,
                                                 theta_T, phi_p, g_p);
    k_attn<<<dim3(25, 32), 256, 0, stream>>>(theta_T, phi_p, g_p, yb);
    k_final<<<dim3(7, 12, 32), 256, 0, stream>>>(yb, wfW, scale, shift, x,
                                                 (float*)d_out);
}